// Round 7
// baseline (146.567 us; speedup 1.0000x reference)
//
#include <hip/hip_runtime.h>
#include <math.h>

#define HH 96
#define WW 96
#define NPIX (HH*WW)          // 9216
#define CC 320
#define GG 32
#define CPG 10                // channels per group
#define TPB 512               // 8 waves; thread = (sextet r=tid>>5, xcl=tid&31)
#define NBLK (16*GG)          // 512 blocks = 2 per CU exactly

typedef _Float16 half4v __attribute__((ext_vector_type(4)));

// ---------------------------------------------------------------------------
// Single fused kernel.
// Phase 1 (per (b,group) block, all 96 rows): depthwise conv once per pixel,
//   accumulate P[b,g,p] = sum_{c in g} (proj_w*gn_w)[c]*conv_c(x)[p]  (fp16)
//   and GN stats s1,s2 of h = conv + dw_b  -> partials[b,g].
// Device-wide barrier (agent-scope atomics; all 512 blocks co-resident:
//   2 blocks/CU, VGPR<=128 via launch_bounds, ~1KB LDS).
// Phase 2 (block (b,gr) -> 288 pixels of batch b): recompute rinv/D from
//   partials, out = sigmoid(sum_g rinv[g]*P[b,g,p] + D).
// ---------------------------------------------------------------------------
__global__ __launch_bounds__(TPB, 4)   // cap VGPR at 128 -> 2 blocks/CU resident
void k_fused(const float* __restrict__ x, const float* __restrict__ dw_w,
             const float* __restrict__ dw_b, const float* __restrict__ gn_w,
             const float* __restrict__ gn_b, const float* __restrict__ proj_w,
             const float* __restrict__ proj_b,
             _Float16* __restrict__ P, float* __restrict__ partials,
             unsigned int* __restrict__ bar, float* __restrict__ out) {
  const int gr = blockIdx.x & 31;
  const int b  = blockIdx.x >> 5;

  __shared__ float wsm[CPG * 9], ssm[CPG], bsm[CPG];
  __shared__ float r1[8], r2[8];
  __shared__ float rs[GG];
  __shared__ float Ds;

  const int tid = threadIdx.x;
  if (tid < CPG * 9) wsm[tid] = dw_w[gr * CPG * 9 + tid];
  if (tid < CPG) {
    int c = gr * CPG + tid;
    ssm[tid] = proj_w[c] * gn_w[c];
    bsm[tid] = dw_b[c];
  }
  __syncthreads();

  // ---------------- phase 1: conv + P planes + stats ----------------
  const int lane = tid & 63;
  const int xcl  = tid & 31;            // 0..31; active if <24
  const int r    = tid >> 5;            // sextet index 0..15 -> rows 6r..6r+5
  const bool active = xcl < 24;
  const float mact  = active ? 1.f : 0.f;
  const int xc = min(xcl, 23);
  const float mlft = (xcl > 0)  ? 1.f : 0.f;
  const float mrgt = (xcl < 23) ? 1.f : 0.f;
  const int lm1 = (xcl >= 1) ? lane - 1 : lane;
  const int lp1 = (xcl < 31) ? lane + 1 : lane;
  const float mtop = (r > 0)  ? 1.f : 0.f;
  const float mbot = (r < 15) ? 1.f : 0.f;

  int offs[8];
  #pragma unroll
  for (int k = 0; k < 8; ++k) {
    int yy = min(max(6 * r - 1 + k, 0), HH - 1);
    offs[k] = yy * WW + xc * 4;
  }
  const float* xg = x + ((size_t)(b * CC + gr * CPG)) * NPIX;

  float p[24];
  #pragma unroll
  for (int i = 0; i < 24; ++i) p[i] = 0.f;
  float s1 = 0.f, s2 = 0.f;

  #pragma unroll 1
  for (int ch = 0; ch < CPG; ++ch) {
    const float* img = xg + ch * NPIX;
    float4 R[8];
    #pragma unroll
    for (int k = 0; k < 8; ++k) R[k] = *(const float4*)(img + offs[k]);
    R[0].x *= mtop; R[0].y *= mtop; R[0].z *= mtop; R[0].w *= mtop;
    R[7].x *= mbot; R[7].y *= mbot; R[7].z *= mbot; R[7].w *= mbot;

    float L[8], T[8];
    #pragma unroll
    for (int k = 0; k < 8; ++k) {
      L[k] = __shfl(R[k].w, lm1) * mlft;
      T[k] = __shfl(R[k].x, lp1) * mrgt;
    }

    const float* wp = &wsm[ch * 9];
    const float w0 = wp[0], w1 = wp[1], w2 = wp[2];
    const float w3 = wp[3], w4 = wp[4], w5 = wp[5];
    const float w6 = wp[6], w7 = wp[7], w8 = wp[8];
    const float sc = ssm[ch], bias = bsm[ch];

    #pragma unroll
    for (int j = 0; j < 6; ++j) {
      const float4 A = R[j], B = R[j + 1], C = R[j + 2];
      const float la = L[j], lb = L[j + 1], lc = L[j + 2];
      const float ta = T[j], tb = T[j + 1], tc = T[j + 2];

      float u0 = w0*la  + w1*A.x + w2*A.y + w3*lb  + w4*B.x + w5*B.y + w6*lc  + w7*C.x + w8*C.y;
      float u1 = w0*A.x + w1*A.y + w2*A.z + w3*B.x + w4*B.y + w5*B.z + w6*C.x + w7*C.y + w8*C.z;
      float u2 = w0*A.y + w1*A.z + w2*A.w + w3*B.y + w4*B.z + w5*B.w + w6*C.y + w7*C.z + w8*C.w;
      float u3 = w0*A.z + w1*A.w + w2*ta  + w3*B.z + w4*B.w + w5*tb  + w6*C.z + w7*C.w + w8*tc;

      p[j*4+0] = fmaf(sc, u0, p[j*4+0]);
      p[j*4+1] = fmaf(sc, u1, p[j*4+1]);
      p[j*4+2] = fmaf(sc, u2, p[j*4+2]);
      p[j*4+3] = fmaf(sc, u3, p[j*4+3]);

      float h0 = u0 + bias, h1 = u1 + bias, h2 = u2 + bias, h3 = u3 + bias;
      s1 += mact * ((h0 + h1) + (h2 + h3));
      s2 += mact * (fmaf(h0, h0, h1 * h1) + fmaf(h2, h2, h3 * h3));
    }
  }

  if (active) {
    _Float16* Pp = P + ((size_t)(b * GG + gr)) * NPIX;
    #pragma unroll
    for (int j = 0; j < 6; ++j) {
      half4v h;
      h.x = (_Float16)p[j*4+0]; h.y = (_Float16)p[j*4+1];
      h.z = (_Float16)p[j*4+2]; h.w = (_Float16)p[j*4+3];
      *(half4v*)&Pp[(size_t)(6 * r + j) * WW + xcl * 4] = h;
    }
  }

  #pragma unroll
  for (int off = 32; off; off >>= 1) {
    s1 += __shfl_down(s1, off);
    s2 += __shfl_down(s2, off);
  }
  if ((tid & 63) == 0) { r1[tid >> 6] = s1; r2[tid >> 6] = s2; }
  __syncthreads();
  if (tid == 0) {
    float a = 0.f, q = 0.f;
    #pragma unroll
    for (int i = 0; i < 8; ++i) { a += r1[i]; q += r2[i]; }
    partials[blockIdx.x * 2]     = a;
    partials[blockIdx.x * 2 + 1] = q;
  }

  // ---------------- device-wide barrier ----------------
  // All 512 blocks are co-resident (2/CU). Publish P+partials with an
  // agent-scope release, spin on the arrival counter with acquire.
  __syncthreads();                 // all block stores issued before arrive
  if (tid == 0) {
    __threadfence();               // belt-and-suspenders device-scope fence
    __hip_atomic_fetch_add(bar, 1u, __ATOMIC_RELEASE, __HIP_MEMORY_SCOPE_AGENT);
    while (__hip_atomic_load(bar, __ATOMIC_ACQUIRE, __HIP_MEMORY_SCOPE_AGENT)
           < (unsigned)NBLK) {
      __builtin_amdgcn_s_sleep(2);
    }
  }
  __syncthreads();                 // block waits for tid0's acquire

  // ---------------- phase 2: rinv/D + gate output ----------------
  if (tid < GG) {
    const int g2 = tid;
    float t1 = partials[(b * GG + g2) * 2];
    float t2 = partials[(b * GG + g2) * 2 + 1];
    const float invN = 1.f / (float)(CPG * NPIX);
    float mean = t1 * invN;
    float var  = t2 * invN - mean * mean;
    float rinv = rsqrtf(var + 1e-5f);
    rs[g2] = rinv;
    float K = 0.f, E = 0.f;
    #pragma unroll
    for (int i = 0; i < CPG; ++i) {
      int c = g2 * CPG + i;
      float pg = proj_w[c] * gn_w[c];
      K = fmaf(pg, dw_b[c] - mean, K);
      E = fmaf(proj_w[c], gn_b[c], E);
    }
    float contrib = fmaf(rinv, K, E);
    #pragma unroll
    for (int m = 16; m; m >>= 1) contrib += __shfl_xor(contrib, m, 32);
    if (g2 == 0) Ds = contrib + proj_b[0];
  }
  __syncthreads();

  // block (b,gr) produces pixels [gr*288, gr*288+288) of batch b
  if (tid < 288) {
    const int px = gr * 288 + tid;
    const _Float16* Pb = P + (size_t)b * GG * NPIX + px;
    float g = 0.f;
    #pragma unroll
    for (int g2 = 0; g2 < GG; ++g2)
      g = fmaf(rs[g2], (float)Pb[(size_t)g2 * NPIX], g);
    g += Ds;
    out[(size_t)b * NPIX + px] = 1.f / (1.f + expf(-g));
  }
}

// ---------------------------------------------------------------------------
extern "C" void kernel_launch(void* const* d_in, const int* in_sizes, int n_in,
                              void* d_out, int out_size, void* d_ws, size_t ws_size,
                              hipStream_t stream) {
  const float* x      = (const float*)d_in[0];
  const float* dw_w   = (const float*)d_in[1];
  const float* dw_b   = (const float*)d_in[2];
  const float* gn_w   = (const float*)d_in[3];
  const float* gn_b   = (const float*)d_in[4];
  const float* proj_w = (const float*)d_in[5];
  const float* proj_b = (const float*)d_in[6];
  float* out = (float*)d_out;

  const size_t P_BYTES = (size_t)16 * GG * NPIX * 2;     // fp16: 9,437,184 B
  _Float16* P         = (_Float16*)d_ws;
  float* partials     = (float*)((char*)d_ws + P_BYTES);          // 1024 f32
  unsigned int* bar   = (unsigned int*)((char*)d_ws + P_BYTES + 8192);

  // reset barrier counter (graph-capture-safe async memset, deterministic)
  hipMemsetAsync((void*)bar, 0, 64, stream);

  hipLaunchKernelGGL(k_fused, dim3(NBLK), dim3(TPB), 0, stream,
                     x, dw_w, dw_b, gn_w, gn_b, proj_w, proj_b,
                     P, partials, bar, out);
}

// Round 8
// 110.968 us; speedup vs baseline: 1.3208x; 1.3208x over previous
//
#include <hip/hip_runtime.h>
#include <math.h>

#define HH 96
#define WW 96
#define NPIX (HH*WW)          // 9216
#define CC 320
#define GG 32
#define CPG 10                // channels per group
#define TPB 512               // 8 waves; thread = (sextet r=tid>>5, xcl=tid&31)
#define NBLK (16*GG)          // 512 blocks = 2 per CU

typedef _Float16 half4v __attribute__((ext_vector_type(4)));

// ---------------------------------------------------------------------------
// Single fused kernel, spill-proof codegen:
//   amdgpu_waves_per_eu(4,4) pins the allocator at the 128-VGPR budget
//   (R7's launch_bounds(512,4) let the heuristic squeeze to 64 VGPR -> scratch
//   spill -> 182us). 128 VGPR + 1.3KB LDS -> exactly 2 blocks/CU resident.
// Phase 1 (block = (b,group), all 96 rows): R6's proven body. Depthwise conv
//   once per pixel; accumulate fp16 P[b,g,p] and GN stats -> partials[b,g].
// Per-BATCH barrier (bar[b], 32 arrivals): early batches start phase 2
//   without waiting for global stragglers.
// Phase 2 (block (b,gr) -> 288 px of batch b): rinv/D from partials,
//   out = sigmoid(sum_g rinv[g]*P[b,g,p] + D).
// ---------------------------------------------------------------------------
__attribute__((amdgpu_waves_per_eu(4, 4)))
__global__ __launch_bounds__(TPB)
void k_fused(const float* __restrict__ x, const float* __restrict__ dw_w,
             const float* __restrict__ dw_b, const float* __restrict__ gn_w,
             const float* __restrict__ gn_b, const float* __restrict__ proj_w,
             const float* __restrict__ proj_b,
             _Float16* __restrict__ P, float* __restrict__ partials,
             unsigned int* __restrict__ bar, float* __restrict__ out) {
  const int gr = blockIdx.x & 31;
  const int b  = blockIdx.x >> 5;

  __shared__ float wsm[CPG * 9], ssm[CPG], bsm[CPG];
  __shared__ float r1[8], r2[8];
  __shared__ float rs[GG];
  __shared__ float Ds;

  const int tid = threadIdx.x;
  if (tid < CPG * 9) wsm[tid] = dw_w[gr * CPG * 9 + tid];
  if (tid < CPG) {
    int c = gr * CPG + tid;
    ssm[tid] = proj_w[c] * gn_w[c];
    bsm[tid] = dw_b[c];
  }
  __syncthreads();

  // ---------------- phase 1: conv + P planes + stats (R6 body) ----------------
  const int lane = tid & 63;
  const int xcl  = tid & 31;            // 0..31; active if <24
  const int r    = tid >> 5;            // sextet index 0..15 -> rows 6r..6r+5
  const bool active = xcl < 24;
  const float mact  = active ? 1.f : 0.f;
  const int xc = min(xcl, 23);
  const float mlft = (xcl > 0)  ? 1.f : 0.f;
  const float mrgt = (xcl < 23) ? 1.f : 0.f;
  const int lm1 = (xcl >= 1) ? lane - 1 : lane;
  const int lp1 = (xcl < 31) ? lane + 1 : lane;
  const float mtop = (r > 0)  ? 1.f : 0.f;
  const float mbot = (r < 15) ? 1.f : 0.f;

  int offs[8];
  #pragma unroll
  for (int k = 0; k < 8; ++k) {
    int yy = min(max(6 * r - 1 + k, 0), HH - 1);
    offs[k] = yy * WW + xc * 4;
  }
  const float* xg = x + ((size_t)(b * CC + gr * CPG)) * NPIX;

  float p[24];
  #pragma unroll
  for (int i = 0; i < 24; ++i) p[i] = 0.f;
  float s1 = 0.f, s2 = 0.f;

  #pragma unroll 1
  for (int ch = 0; ch < CPG; ++ch) {
    const float* img = xg + ch * NPIX;
    float4 R[8];
    #pragma unroll
    for (int k = 0; k < 8; ++k) R[k] = *(const float4*)(img + offs[k]);
    R[0].x *= mtop; R[0].y *= mtop; R[0].z *= mtop; R[0].w *= mtop;
    R[7].x *= mbot; R[7].y *= mbot; R[7].z *= mbot; R[7].w *= mbot;

    float L[8], T[8];
    #pragma unroll
    for (int k = 0; k < 8; ++k) {
      L[k] = __shfl(R[k].w, lm1) * mlft;
      T[k] = __shfl(R[k].x, lp1) * mrgt;
    }

    const float* wp = &wsm[ch * 9];
    const float w0 = wp[0], w1 = wp[1], w2 = wp[2];
    const float w3 = wp[3], w4 = wp[4], w5 = wp[5];
    const float w6 = wp[6], w7 = wp[7], w8 = wp[8];
    const float sc = ssm[ch], bias = bsm[ch];

    #pragma unroll
    for (int j = 0; j < 6; ++j) {
      const float4 A = R[j], B = R[j + 1], C = R[j + 2];
      const float la = L[j], lb = L[j + 1], lc = L[j + 2];
      const float ta = T[j], tb = T[j + 1], tc = T[j + 2];

      float u0 = w0*la  + w1*A.x + w2*A.y + w3*lb  + w4*B.x + w5*B.y + w6*lc  + w7*C.x + w8*C.y;
      float u1 = w0*A.x + w1*A.y + w2*A.z + w3*B.x + w4*B.y + w5*B.z + w6*C.x + w7*C.y + w8*C.z;
      float u2 = w0*A.y + w1*A.z + w2*A.w + w3*B.y + w4*B.z + w5*B.w + w6*C.y + w7*C.z + w8*C.w;
      float u3 = w0*A.z + w1*A.w + w2*ta  + w3*B.z + w4*B.w + w5*tb  + w6*C.z + w7*C.w + w8*tc;

      p[j*4+0] = fmaf(sc, u0, p[j*4+0]);
      p[j*4+1] = fmaf(sc, u1, p[j*4+1]);
      p[j*4+2] = fmaf(sc, u2, p[j*4+2]);
      p[j*4+3] = fmaf(sc, u3, p[j*4+3]);

      float h0 = u0 + bias, h1 = u1 + bias, h2 = u2 + bias, h3 = u3 + bias;
      s1 += mact * ((h0 + h1) + (h2 + h3));
      s2 += mact * (fmaf(h0, h0, h1 * h1) + fmaf(h2, h2, h3 * h3));
    }
  }

  if (active) {
    _Float16* Pp = P + ((size_t)(b * GG + gr)) * NPIX;
    #pragma unroll
    for (int j = 0; j < 6; ++j) {
      half4v h;
      h.x = (_Float16)p[j*4+0]; h.y = (_Float16)p[j*4+1];
      h.z = (_Float16)p[j*4+2]; h.w = (_Float16)p[j*4+3];
      *(half4v*)&Pp[(size_t)(6 * r + j) * WW + xcl * 4] = h;
    }
  }

  #pragma unroll
  for (int off = 32; off; off >>= 1) {
    s1 += __shfl_down(s1, off);
    s2 += __shfl_down(s2, off);
  }
  if ((tid & 63) == 0) { r1[tid >> 6] = s1; r2[tid >> 6] = s2; }
  __syncthreads();
  if (tid == 0) {
    float a = 0.f, q = 0.f;
    #pragma unroll
    for (int i = 0; i < 8; ++i) { a += r1[i]; q += r2[i]; }
    partials[blockIdx.x * 2]     = a;
    partials[blockIdx.x * 2 + 1] = q;
  }

  // ---------------- per-batch barrier ----------------
  // All 512 blocks co-resident (2/CU at <=128 VGPR). The 32 blocks of batch b
  // rendezvous on bar[b]; release publishes P+partials, acquire consumes.
  __syncthreads();                 // all block stores issued before arrive
  if (tid == 0) {
    __threadfence();               // device-scope publish
    __hip_atomic_fetch_add(&bar[b], 1u, __ATOMIC_RELEASE, __HIP_MEMORY_SCOPE_AGENT);
    while (__hip_atomic_load(&bar[b], __ATOMIC_ACQUIRE, __HIP_MEMORY_SCOPE_AGENT)
           < (unsigned)GG) {
      __builtin_amdgcn_s_sleep(2);
    }
  }
  __syncthreads();                 // block waits for tid0's acquire

  // ---------------- phase 2: rinv/D + gate output ----------------
  if (tid < GG) {
    const int g2 = tid;
    float t1 = partials[(b * GG + g2) * 2];
    float t2 = partials[(b * GG + g2) * 2 + 1];
    const float invN = 1.f / (float)(CPG * NPIX);
    float mean = t1 * invN;
    float var  = t2 * invN - mean * mean;
    float rinv = rsqrtf(var + 1e-5f);
    rs[g2] = rinv;
    float K = 0.f, E = 0.f;
    #pragma unroll
    for (int i = 0; i < CPG; ++i) {
      int c = g2 * CPG + i;
      float pg = proj_w[c] * gn_w[c];
      K = fmaf(pg, dw_b[c] - mean, K);
      E = fmaf(proj_w[c], gn_b[c], E);
    }
    float contrib = fmaf(rinv, K, E);
    #pragma unroll
    for (int m = 16; m; m >>= 1) contrib += __shfl_xor(contrib, m, 32);
    if (g2 == 0) Ds = contrib + proj_b[0];
  }
  __syncthreads();

  // block (b,gr) produces pixels [gr*288, gr*288+288) of batch b
  if (tid < 288) {
    const int px = gr * 288 + tid;
    const _Float16* Pb = P + (size_t)b * GG * NPIX + px;
    float g = 0.f;
    #pragma unroll
    for (int g2 = 0; g2 < GG; ++g2)
      g = fmaf(rs[g2], (float)Pb[(size_t)g2 * NPIX], g);
    g += Ds;
    out[(size_t)b * NPIX + px] = 1.f / (1.f + expf(-g));
  }
}

// ---------------------------------------------------------------------------
extern "C" void kernel_launch(void* const* d_in, const int* in_sizes, int n_in,
                              void* d_out, int out_size, void* d_ws, size_t ws_size,
                              hipStream_t stream) {
  const float* x      = (const float*)d_in[0];
  const float* dw_w   = (const float*)d_in[1];
  const float* dw_b   = (const float*)d_in[2];
  const float* gn_w   = (const float*)d_in[3];
  const float* gn_b   = (const float*)d_in[4];
  const float* proj_w = (const float*)d_in[5];
  const float* proj_b = (const float*)d_in[6];
  float* out = (float*)d_out;

  const size_t P_BYTES = (size_t)16 * GG * NPIX * 2;     // fp16: 9,437,184 B
  _Float16* P         = (_Float16*)d_ws;
  float* partials     = (float*)((char*)d_ws + P_BYTES);          // 1024 f32
  unsigned int* bar   = (unsigned int*)((char*)d_ws + P_BYTES + 8192);

  // reset the 16 per-batch barrier counters (graph-capture-safe)
  hipMemsetAsync((void*)bar, 0, 64, stream);

  hipLaunchKernelGGL(k_fused, dim3(NBLK), dim3(TPB), 0, stream,
                     x, dw_w, dw_b, gn_w, gn_b, proj_w, proj_b,
                     P, partials, bar, out);
}

// Round 9
// 46.905 us; speedup vs baseline: 3.1248x; 2.3658x over previous
//
#include <hip/hip_runtime.h>
#include <math.h>

#define HH 96
#define WW 96
#define NPIX (HH*WW)          // 9216
#define CC 320
#define GG 32
#define CPG 10                // channels per group
#define YT 6                  // y-tiles per image (16 rows each)
#define TPB 256               // 4 waves; thread = (row-pair r=tid>>5, xcl=tid&31)

// ---------------------------------------------------------------------------
// Kernel 1 (single pass over x): block = (b, group, ytile of 16 rows).
// Thread (r, xcl) owns rows Y0=yt*16+2r, Y1=Y0+1, pixels [3*xcl, 3*xcl+3):
// 3 px/lane x 32 lanes = 96 px = full row -> 100% lane utilization (previous
// rounds idled 8/32 lanes => 75% cap on all issue slots, the observed 4.2TB/s).
// Per channel: 4 float3 row loads (dwordx3, rows Y0-1..Y1+1, clamped+masked),
// halo px via wave shfl, 3x3 conv for 6 px, accumulating
//   p[j]  += (proj_w*gn_w)[c] * u            (stats-independent plane, fp32)
//   s1,s2 += h, h^2  with h = u + dw_b[c]    (GN statistics)
// Small body (~57 live VGPRs) fits the 64-VGPR cap from launch_bounds(256,8)
// -> 8 waves/SIMD for latency hiding (R6 ran at 4).
// ---------------------------------------------------------------------------
__global__ __launch_bounds__(TPB, 8)
void k_main(const float* __restrict__ x, const float* __restrict__ dw_w,
            const float* __restrict__ dw_b, const float* __restrict__ gn_w,
            const float* __restrict__ proj_w,
            float* __restrict__ P, float* __restrict__ partials) {
  const int bid = blockIdx.x;
  const int yt = bid % YT;
  const int t  = bid / YT;
  const int gr = t & 31;
  const int b  = t >> 5;

  __shared__ float wsm[CPG * 9], ssm[CPG], bsm[CPG];
  const int tid = threadIdx.x;
  if (tid < CPG * 9) wsm[tid] = dw_w[gr * CPG * 9 + tid];
  if (tid < CPG) {
    int c = gr * CPG + tid;
    ssm[tid] = proj_w[c] * gn_w[c];
    bsm[tid] = dw_b[c];
  }
  __syncthreads();

  const int lane = tid & 63;
  const int xcl  = tid & 31;            // 0..31, ALL active
  const int r    = tid >> 5;            // row-pair 0..7
  const int col0 = 3 * xcl;             // first owned pixel column
  const int Y0 = yt * 16 + 2 * r;
  const int Y1 = Y0 + 1;

  const float mtop = (Y0 > 0)      ? 1.f : 0.f;
  const float mbot = (Y1 < HH - 1) ? 1.f : 0.f;
  const int ya = max(Y0 - 1, 0);
  const int yd = min(Y1 + 1, HH - 1);
  const float mlft = (xcl > 0)  ? 1.f : 0.f;
  const float mrgt = (xcl < 31) ? 1.f : 0.f;
  const int lm1 = (xcl >= 1) ? lane - 1 : lane;   // within 32-lane row group
  const int lp1 = (xcl < 31) ? lane + 1 : lane;

  const int offa = ya * WW + col0;
  const int offb = Y0 * WW + col0;
  const int offc = Y1 * WW + col0;
  const int offd = yd * WW + col0;
  const float* xg = x + ((size_t)(b * CC + gr * CPG)) * NPIX;

  float p0=0.f,p1=0.f,p2=0.f,p3=0.f,p4=0.f,p5=0.f;
  float s1 = 0.f, s2 = 0.f;

  #pragma unroll 1
  for (int ch = 0; ch < CPG; ++ch) {
    const float* img = xg + ch * NPIX;
    float3 A = *(const float3*)(img + offa);
    float3 B = *(const float3*)(img + offb);
    float3 C = *(const float3*)(img + offc);
    float3 D = *(const float3*)(img + offd);
    A.x *= mtop; A.y *= mtop; A.z *= mtop;
    D.x *= mbot; D.y *= mbot; D.z *= mbot;

    // halo pixels from wave neighbors (mask AFTER row-mask so edges are 0)
    float La = __shfl(A.z, lm1) * mlft;
    float Lb = __shfl(B.z, lm1) * mlft;
    float Lc = __shfl(C.z, lm1) * mlft;
    float Ld = __shfl(D.z, lm1) * mlft;
    float Ta = __shfl(A.x, lp1) * mrgt;
    float Tb = __shfl(B.x, lp1) * mrgt;
    float Tc = __shfl(C.x, lp1) * mrgt;
    float Td = __shfl(D.x, lp1) * mrgt;

    const float* wp = &wsm[ch * 9];
    const float w0 = wp[0], w1 = wp[1], w2 = wp[2];
    const float w3 = wp[3], w4 = wp[4], w5 = wp[5];
    const float w6 = wp[6], w7 = wp[7], w8 = wp[8];
    const float sc = ssm[ch], bias = bsm[ch];

    // row Y0 (A,B,C)
    float u0 = w0*La  + w1*A.x + w2*A.y + w3*Lb  + w4*B.x + w5*B.y + w6*Lc  + w7*C.x + w8*C.y;
    float u1 = w0*A.x + w1*A.y + w2*A.z + w3*B.x + w4*B.y + w5*B.z + w6*C.x + w7*C.y + w8*C.z;
    float u2 = w0*A.y + w1*A.z + w2*Ta  + w3*B.y + w4*B.z + w5*Tb  + w6*C.y + w7*C.z + w8*Tc;
    // row Y1 (B,C,D)
    float u3 = w0*Lb  + w1*B.x + w2*B.y + w3*Lc  + w4*C.x + w5*C.y + w6*Ld  + w7*D.x + w8*D.y;
    float u4 = w0*B.x + w1*B.y + w2*B.z + w3*C.x + w4*C.y + w5*C.z + w6*D.x + w7*D.y + w8*D.z;
    float u5 = w0*B.y + w1*B.z + w2*Tb  + w3*C.y + w4*C.z + w5*Tc  + w6*D.y + w7*D.z + w8*Td;

    p0 = fmaf(sc, u0, p0); p1 = fmaf(sc, u1, p1); p2 = fmaf(sc, u2, p2);
    p3 = fmaf(sc, u3, p3); p4 = fmaf(sc, u4, p4); p5 = fmaf(sc, u5, p5);

    float h0 = u0 + bias, h1 = u1 + bias, h2 = u2 + bias;
    float h3 = u3 + bias, h4 = u4 + bias, h5 = u5 + bias;
    s1 += ((h0 + h1) + (h2 + h3)) + (h4 + h5);
    float q0 = fmaf(h0, h0, h1 * h1);
    float q1 = fmaf(h2, h2, h3 * h3);
    float q2 = fmaf(h4, h4, h5 * h5);
    s2 += (q0 + q1) + q2;
  }

  {
    float* Pp = P + ((size_t)(b * GG + gr)) * NPIX;
    float3 v0; v0.x = p0; v0.y = p1; v0.z = p2;
    float3 v1; v1.x = p3; v1.y = p4; v1.z = p5;
    *(float3*)&Pp[offb] = v0;
    *(float3*)&Pp[offc] = v1;
  }

  // block-reduce s1,s2 (4 waves)
  #pragma unroll
  for (int off = 32; off; off >>= 1) {
    s1 += __shfl_down(s1, off);
    s2 += __shfl_down(s2, off);
  }
  __shared__ float r1[4], r2[4];
  if ((tid & 63) == 0) { r1[tid >> 6] = s1; r2[tid >> 6] = s2; }
  __syncthreads();
  if (tid == 0) {
    float a = r1[0] + r1[1] + r1[2] + r1[3];
    float q = r2[0] + r2[1] + r2[2] + r2[3];
    partials[bid * 2]     = a;
    partials[bid * 2 + 1] = q;
  }
}

// ---------------------------------------------------------------------------
// Kernel 2: fused coef + output. Each block (18 per batch) recomputes its
// batch's 32 rinv values + scalar D from partials, then
// out[b,p] = sigmoid( sum_g rinv[g]*P[b,g,p] + D ).  128 thr, 4 px/thread.
// ---------------------------------------------------------------------------
__global__ __launch_bounds__(128)
void k_out(const float* __restrict__ P, const float* __restrict__ partials,
           const float* __restrict__ dw_b, const float* __restrict__ gn_w,
           const float* __restrict__ gn_b, const float* __restrict__ proj_w,
           const float* __restrict__ proj_b, float* __restrict__ out) {
  const int b   = blockIdx.x / 18;
  const int blk = blockIdx.x % 18;
  __shared__ float rs[GG];
  __shared__ float Ds;

  if (threadIdx.x < GG) {
    const int gr = threadIdx.x;
    float s1 = 0.f, s2 = 0.f;
    #pragma unroll
    for (int t = 0; t < YT; ++t) {
      int o = (((b * GG + gr) * YT) + t) * 2;
      s1 += partials[o];
      s2 += partials[o + 1];
    }
    const float invN = 1.f / (float)(CPG * NPIX);
    float mean = s1 * invN;
    float var  = s2 * invN - mean * mean;
    float rinv = rsqrtf(var + 1e-5f);
    rs[gr] = rinv;
    float K = 0.f, E = 0.f;
    #pragma unroll
    for (int i = 0; i < CPG; ++i) {
      int c = gr * CPG + i;
      float pg = proj_w[c] * gn_w[c];
      K = fmaf(pg, dw_b[c] - mean, K);
      E = fmaf(proj_w[c], gn_b[c], E);
    }
    float contrib = fmaf(rinv, K, E);
    #pragma unroll
    for (int m = 16; m; m >>= 1) contrib += __shfl_xor(contrib, m, 32);
    if (gr == 0) Ds = contrib + proj_b[0];
  }
  __syncthreads();

  const int p = (blk * 128 + threadIdx.x) * 4;    // 18*128*4 = 9216
  const float* Pb = P + (size_t)b * GG * NPIX + p;
  float g0 = 0.f, g1 = 0.f, g2 = 0.f, g3 = 0.f;
  #pragma unroll
  for (int gr = 0; gr < GG; ++gr) {
    float4 v = *(const float4*)(Pb + (size_t)gr * NPIX);
    float rr = rs[gr];
    g0 = fmaf(rr, v.x, g0);
    g1 = fmaf(rr, v.y, g1);
    g2 = fmaf(rr, v.z, g2);
    g3 = fmaf(rr, v.w, g3);
  }
  const float d = Ds;
  float4 o;
  o.x = 1.f / (1.f + expf(-(g0 + d)));
  o.y = 1.f / (1.f + expf(-(g1 + d)));
  o.z = 1.f / (1.f + expf(-(g2 + d)));
  o.w = 1.f / (1.f + expf(-(g3 + d)));
  *(float4*)&out[(size_t)b * NPIX + p] = o;
}

// ---------------------------------------------------------------------------
extern "C" void kernel_launch(void* const* d_in, const int* in_sizes, int n_in,
                              void* d_out, int out_size, void* d_ws, size_t ws_size,
                              hipStream_t stream) {
  const float* x      = (const float*)d_in[0];
  const float* dw_w   = (const float*)d_in[1];
  const float* dw_b   = (const float*)d_in[2];
  const float* gn_w   = (const float*)d_in[3];
  const float* gn_b   = (const float*)d_in[4];
  const float* proj_w = (const float*)d_in[5];
  const float* proj_b = (const float*)d_in[6];
  float* out = (float*)d_out;

  const size_t P_BYTES = (size_t)16 * GG * NPIX * 4;     // fp32: 18,874,368 B
  float* P        = (float*)d_ws;
  float* partials = (float*)((char*)d_ws + P_BYTES);     // 3072*2 f32

  hipLaunchKernelGGL(k_main, dim3(16 * GG * YT), dim3(TPB), 0, stream,
                     x, dw_w, dw_b, gn_w, proj_w, P, partials);
  hipLaunchKernelGGL(k_out, dim3(16 * 18), dim3(128), 0, stream,
                     P, partials, dw_b, gn_w, gn_b, proj_w, proj_b, out);
}

// Round 10
// 46.900 us; speedup vs baseline: 3.1251x; 1.0001x over previous
//
#include <hip/hip_runtime.h>
#include <math.h>

#define HH 96
#define WW 96
#define NPIX (HH*WW)          // 9216
#define CC 320
#define GG 32
#define CPG 10                // channels per group
#define YT 6                  // y-tiles per image (16 rows each)
#define TPB 256               // 4 waves; thread = (row-pair r=tid>>5, xcl=tid&31)

// ---------------------------------------------------------------------------
// Kernel 1 (single pass over x): block = (b, group, ytile of 16 rows).
// Thread (r, xcl) owns rows Y0=yt*16+2r, Y1=Y0+1, pixels [3*xcl, 3*xcl+3):
// 3 px/lane x 32 lanes = 96 px = full row -> 100% lane utilization (previous
// rounds idled 8/32 lanes => 75% cap on all issue slots, the observed 4.2TB/s).
// Per channel: 4 float3 row loads (dwordx3, rows Y0-1..Y1+1, clamped+masked),
// halo px via wave shfl, 3x3 conv for 6 px, accumulating
//   p[j]  += (proj_w*gn_w)[c] * u            (stats-independent plane, fp32)
//   s1,s2 += h, h^2  with h = u + dw_b[c]    (GN statistics)
// Small body (~57 live VGPRs) fits the 64-VGPR cap from launch_bounds(256,8)
// -> 8 waves/SIMD for latency hiding (R6 ran at 4).
// ---------------------------------------------------------------------------
__global__ __launch_bounds__(TPB, 8)
void k_main(const float* __restrict__ x, const float* __restrict__ dw_w,
            const float* __restrict__ dw_b, const float* __restrict__ gn_w,
            const float* __restrict__ proj_w,
            float* __restrict__ P, float* __restrict__ partials) {
  const int bid = blockIdx.x;
  const int yt = bid % YT;
  const int t  = bid / YT;
  const int gr = t & 31;
  const int b  = t >> 5;

  __shared__ float wsm[CPG * 9], ssm[CPG], bsm[CPG];
  const int tid = threadIdx.x;
  if (tid < CPG * 9) wsm[tid] = dw_w[gr * CPG * 9 + tid];
  if (tid < CPG) {
    int c = gr * CPG + tid;
    ssm[tid] = proj_w[c] * gn_w[c];
    bsm[tid] = dw_b[c];
  }
  __syncthreads();

  const int lane = tid & 63;
  const int xcl  = tid & 31;            // 0..31, ALL active
  const int r    = tid >> 5;            // row-pair 0..7
  const int col0 = 3 * xcl;             // first owned pixel column
  const int Y0 = yt * 16 + 2 * r;
  const int Y1 = Y0 + 1;

  const float mtop = (Y0 > 0)      ? 1.f : 0.f;
  const float mbot = (Y1 < HH - 1) ? 1.f : 0.f;
  const int ya = max(Y0 - 1, 0);
  const int yd = min(Y1 + 1, HH - 1);
  const float mlft = (xcl > 0)  ? 1.f : 0.f;
  const float mrgt = (xcl < 31) ? 1.f : 0.f;
  const int lm1 = (xcl >= 1) ? lane - 1 : lane;   // within 32-lane row group
  const int lp1 = (xcl < 31) ? lane + 1 : lane;

  const int offa = ya * WW + col0;
  const int offb = Y0 * WW + col0;
  const int offc = Y1 * WW + col0;
  const int offd = yd * WW + col0;
  const float* xg = x + ((size_t)(b * CC + gr * CPG)) * NPIX;

  float p0=0.f,p1=0.f,p2=0.f,p3=0.f,p4=0.f,p5=0.f;
  float s1 = 0.f, s2 = 0.f;

  #pragma unroll 1
  for (int ch = 0; ch < CPG; ++ch) {
    const float* img = xg + ch * NPIX;
    float3 A = *(const float3*)(img + offa);
    float3 B = *(const float3*)(img + offb);
    float3 C = *(const float3*)(img + offc);
    float3 D = *(const float3*)(img + offd);
    A.x *= mtop; A.y *= mtop; A.z *= mtop;
    D.x *= mbot; D.y *= mbot; D.z *= mbot;

    // halo pixels from wave neighbors (mask AFTER row-mask so edges are 0)
    float La = __shfl(A.z, lm1) * mlft;
    float Lb = __shfl(B.z, lm1) * mlft;
    float Lc = __shfl(C.z, lm1) * mlft;
    float Ld = __shfl(D.z, lm1) * mlft;
    float Ta = __shfl(A.x, lp1) * mrgt;
    float Tb = __shfl(B.x, lp1) * mrgt;
    float Tc = __shfl(C.x, lp1) * mrgt;
    float Td = __shfl(D.x, lp1) * mrgt;

    const float* wp = &wsm[ch * 9];
    const float w0 = wp[0], w1 = wp[1], w2 = wp[2];
    const float w3 = wp[3], w4 = wp[4], w5 = wp[5];
    const float w6 = wp[6], w7 = wp[7], w8 = wp[8];
    const float sc = ssm[ch], bias = bsm[ch];

    // row Y0 (A,B,C)
    float u0 = w0*La  + w1*A.x + w2*A.y + w3*Lb  + w4*B.x + w5*B.y + w6*Lc  + w7*C.x + w8*C.y;
    float u1 = w0*A.x + w1*A.y + w2*A.z + w3*B.x + w4*B.y + w5*B.z + w6*C.x + w7*C.y + w8*C.z;
    float u2 = w0*A.y + w1*A.z + w2*Ta  + w3*B.y + w4*B.z + w5*Tb  + w6*C.y + w7*C.z + w8*Tc;
    // row Y1 (B,C,D)
    float u3 = w0*Lb  + w1*B.x + w2*B.y + w3*Lc  + w4*C.x + w5*C.y + w6*Ld  + w7*D.x + w8*D.y;
    float u4 = w0*B.x + w1*B.y + w2*B.z + w3*C.x + w4*C.y + w5*C.z + w6*D.x + w7*D.y + w8*D.z;
    float u5 = w0*B.y + w1*B.z + w2*Tb  + w3*C.y + w4*C.z + w5*Tc  + w6*D.y + w7*D.z + w8*Td;

    p0 = fmaf(sc, u0, p0); p1 = fmaf(sc, u1, p1); p2 = fmaf(sc, u2, p2);
    p3 = fmaf(sc, u3, p3); p4 = fmaf(sc, u4, p4); p5 = fmaf(sc, u5, p5);

    float h0 = u0 + bias, h1 = u1 + bias, h2 = u2 + bias;
    float h3 = u3 + bias, h4 = u4 + bias, h5 = u5 + bias;
    s1 += ((h0 + h1) + (h2 + h3)) + (h4 + h5);
    float q0 = fmaf(h0, h0, h1 * h1);
    float q1 = fmaf(h2, h2, h3 * h3);
    float q2 = fmaf(h4, h4, h5 * h5);
    s2 += (q0 + q1) + q2;
  }

  {
    float* Pp = P + ((size_t)(b * GG + gr)) * NPIX;
    float3 v0; v0.x = p0; v0.y = p1; v0.z = p2;
    float3 v1; v1.x = p3; v1.y = p4; v1.z = p5;
    *(float3*)&Pp[offb] = v0;
    *(float3*)&Pp[offc] = v1;
  }

  // block-reduce s1,s2 (4 waves)
  #pragma unroll
  for (int off = 32; off; off >>= 1) {
    s1 += __shfl_down(s1, off);
    s2 += __shfl_down(s2, off);
  }
  __shared__ float r1[4], r2[4];
  if ((tid & 63) == 0) { r1[tid >> 6] = s1; r2[tid >> 6] = s2; }
  __syncthreads();
  if (tid == 0) {
    float a = r1[0] + r1[1] + r1[2] + r1[3];
    float q = r2[0] + r2[1] + r2[2] + r2[3];
    partials[bid * 2]     = a;
    partials[bid * 2 + 1] = q;
  }
}

// ---------------------------------------------------------------------------
// Kernel 2: fused coef + output. Each block (18 per batch) recomputes its
// batch's 32 rinv values + scalar D from partials, then
// out[b,p] = sigmoid( sum_g rinv[g]*P[b,g,p] + D ).  128 thr, 4 px/thread.
// ---------------------------------------------------------------------------
__global__ __launch_bounds__(128)
void k_out(const float* __restrict__ P, const float* __restrict__ partials,
           const float* __restrict__ dw_b, const float* __restrict__ gn_w,
           const float* __restrict__ gn_b, const float* __restrict__ proj_w,
           const float* __restrict__ proj_b, float* __restrict__ out) {
  const int b   = blockIdx.x / 18;
  const int blk = blockIdx.x % 18;
  __shared__ float rs[GG];
  __shared__ float Ds;

  if (threadIdx.x < GG) {
    const int gr = threadIdx.x;
    float s1 = 0.f, s2 = 0.f;
    #pragma unroll
    for (int t = 0; t < YT; ++t) {
      int o = (((b * GG + gr) * YT) + t) * 2;
      s1 += partials[o];
      s2 += partials[o + 1];
    }
    const float invN = 1.f / (float)(CPG * NPIX);
    float mean = s1 * invN;
    float var  = s2 * invN - mean * mean;
    float rinv = rsqrtf(var + 1e-5f);
    rs[gr] = rinv;
    float K = 0.f, E = 0.f;
    #pragma unroll
    for (int i = 0; i < CPG; ++i) {
      int c = gr * CPG + i;
      float pg = proj_w[c] * gn_w[c];
      K = fmaf(pg, dw_b[c] - mean, K);
      E = fmaf(proj_w[c], gn_b[c], E);
    }
    float contrib = fmaf(rinv, K, E);
    #pragma unroll
    for (int m = 16; m; m >>= 1) contrib += __shfl_xor(contrib, m, 32);
    if (gr == 0) Ds = contrib + proj_b[0];
  }
  __syncthreads();

  const int p = (blk * 128 + threadIdx.x) * 4;    // 18*128*4 = 9216
  const float* Pb = P + (size_t)b * GG * NPIX + p;
  float g0 = 0.f, g1 = 0.f, g2 = 0.f, g3 = 0.f;
  #pragma unroll
  for (int gr = 0; gr < GG; ++gr) {
    float4 v = *(const float4*)(Pb + (size_t)gr * NPIX);
    float rr = rs[gr];
    g0 = fmaf(rr, v.x, g0);
    g1 = fmaf(rr, v.y, g1);
    g2 = fmaf(rr, v.z, g2);
    g3 = fmaf(rr, v.w, g3);
  }
  const float d = Ds;
  float4 o;
  o.x = 1.f / (1.f + expf(-(g0 + d)));
  o.y = 1.f / (1.f + expf(-(g1 + d)));
  o.z = 1.f / (1.f + expf(-(g2 + d)));
  o.w = 1.f / (1.f + expf(-(g3 + d)));
  *(float4*)&out[(size_t)b * NPIX + p] = o;
}

// ---------------------------------------------------------------------------
extern "C" void kernel_launch(void* const* d_in, const int* in_sizes, int n_in,
                              void* d_out, int out_size, void* d_ws, size_t ws_size,
                              hipStream_t stream) {
  const float* x      = (const float*)d_in[0];
  const float* dw_w   = (const float*)d_in[1];
  const float* dw_b   = (const float*)d_in[2];
  const float* gn_w   = (const float*)d_in[3];
  const float* gn_b   = (const float*)d_in[4];
  const float* proj_w = (const float*)d_in[5];
  const float* proj_b = (const float*)d_in[6];
  float* out = (float*)d_out;

  const size_t P_BYTES = (size_t)16 * GG * NPIX * 4;     // fp32: 18,874,368 B
  float* P        = (float*)d_ws;
  float* partials = (float*)((char*)d_ws + P_BYTES);     // 3072*2 f32

  hipLaunchKernelGGL(k_main, dim3(16 * GG * YT), dim3(TPB), 0, stream,
                     x, dw_w, dw_b, gn_w, proj_w, P, partials);
  hipLaunchKernelGGL(k_out, dim3(16 * 18), dim3(128), 0, stream,
                     P, partials, dw_b, gn_w, gn_b, proj_w, proj_b, out);
}

// Round 11
// 46.837 us; speedup vs baseline: 3.1293x; 1.0013x over previous
//
#include <hip/hip_runtime.h>
#include <math.h>

#define HH 96
#define WW 96
#define NPIX (HH*WW)          // 9216
#define CC 320
#define GG 32
#define CPG 10                // channels per group
#define YT 6                  // y-tiles per image (16 rows each)
#define TPB 256               // 4 waves; thread = (row-pair r=tid>>5, xcl=tid&31)

// ---------------------------------------------------------------------------
// Kernel 1 (single pass over x): block = (b, group, ytile of 16 rows).
// Thread (r, xcl) owns rows Y0=yt*16+2r, Y1=Y0+1, pixels [3*xcl, 3*xcl+3):
// 3 px/lane x 32 lanes = 96 px = full row -> 100% lane utilization (previous
// rounds idled 8/32 lanes => 75% cap on all issue slots, the observed 4.2TB/s).
// Per channel: 4 float3 row loads (dwordx3, rows Y0-1..Y1+1, clamped+masked),
// halo px via wave shfl, 3x3 conv for 6 px, accumulating
//   p[j]  += (proj_w*gn_w)[c] * u            (stats-independent plane, fp32)
//   s1,s2 += h, h^2  with h = u + dw_b[c]    (GN statistics)
// Small body (~57 live VGPRs) fits the 64-VGPR cap from launch_bounds(256,8)
// -> 8 waves/SIMD for latency hiding (R6 ran at 4).
// ---------------------------------------------------------------------------
__global__ __launch_bounds__(TPB, 8)
void k_main(const float* __restrict__ x, const float* __restrict__ dw_w,
            const float* __restrict__ dw_b, const float* __restrict__ gn_w,
            const float* __restrict__ proj_w,
            float* __restrict__ P, float* __restrict__ partials) {
  const int bid = blockIdx.x;
  const int yt = bid % YT;
  const int t  = bid / YT;
  const int gr = t & 31;
  const int b  = t >> 5;

  __shared__ float wsm[CPG * 9], ssm[CPG], bsm[CPG];
  const int tid = threadIdx.x;
  if (tid < CPG * 9) wsm[tid] = dw_w[gr * CPG * 9 + tid];
  if (tid < CPG) {
    int c = gr * CPG + tid;
    ssm[tid] = proj_w[c] * gn_w[c];
    bsm[tid] = dw_b[c];
  }
  __syncthreads();

  const int lane = tid & 63;
  const int xcl  = tid & 31;            // 0..31, ALL active
  const int r    = tid >> 5;            // row-pair 0..7
  const int col0 = 3 * xcl;             // first owned pixel column
  const int Y0 = yt * 16 + 2 * r;
  const int Y1 = Y0 + 1;

  const float mtop = (Y0 > 0)      ? 1.f : 0.f;
  const float mbot = (Y1 < HH - 1) ? 1.f : 0.f;
  const int ya = max(Y0 - 1, 0);
  const int yd = min(Y1 + 1, HH - 1);
  const float mlft = (xcl > 0)  ? 1.f : 0.f;
  const float mrgt = (xcl < 31) ? 1.f : 0.f;
  const int lm1 = (xcl >= 1) ? lane - 1 : lane;   // within 32-lane row group
  const int lp1 = (xcl < 31) ? lane + 1 : lane;

  const int offa = ya * WW + col0;
  const int offb = Y0 * WW + col0;
  const int offc = Y1 * WW + col0;
  const int offd = yd * WW + col0;
  const float* xg = x + ((size_t)(b * CC + gr * CPG)) * NPIX;

  float p0=0.f,p1=0.f,p2=0.f,p3=0.f,p4=0.f,p5=0.f;
  float s1 = 0.f, s2 = 0.f;

  #pragma unroll 1
  for (int ch = 0; ch < CPG; ++ch) {
    const float* img = xg + ch * NPIX;
    float3 A = *(const float3*)(img + offa);
    float3 B = *(const float3*)(img + offb);
    float3 C = *(const float3*)(img + offc);
    float3 D = *(const float3*)(img + offd);
    A.x *= mtop; A.y *= mtop; A.z *= mtop;
    D.x *= mbot; D.y *= mbot; D.z *= mbot;

    // halo pixels from wave neighbors (mask AFTER row-mask so edges are 0)
    float La = __shfl(A.z, lm1) * mlft;
    float Lb = __shfl(B.z, lm1) * mlft;
    float Lc = __shfl(C.z, lm1) * mlft;
    float Ld = __shfl(D.z, lm1) * mlft;
    float Ta = __shfl(A.x, lp1) * mrgt;
    float Tb = __shfl(B.x, lp1) * mrgt;
    float Tc = __shfl(C.x, lp1) * mrgt;
    float Td = __shfl(D.x, lp1) * mrgt;

    const float* wp = &wsm[ch * 9];
    const float w0 = wp[0], w1 = wp[1], w2 = wp[2];
    const float w3 = wp[3], w4 = wp[4], w5 = wp[5];
    const float w6 = wp[6], w7 = wp[7], w8 = wp[8];
    const float sc = ssm[ch], bias = bsm[ch];

    // row Y0 (A,B,C)
    float u0 = w0*La  + w1*A.x + w2*A.y + w3*Lb  + w4*B.x + w5*B.y + w6*Lc  + w7*C.x + w8*C.y;
    float u1 = w0*A.x + w1*A.y + w2*A.z + w3*B.x + w4*B.y + w5*B.z + w6*C.x + w7*C.y + w8*C.z;
    float u2 = w0*A.y + w1*A.z + w2*Ta  + w3*B.y + w4*B.z + w5*Tb  + w6*C.y + w7*C.z + w8*Tc;
    // row Y1 (B,C,D)
    float u3 = w0*Lb  + w1*B.x + w2*B.y + w3*Lc  + w4*C.x + w5*C.y + w6*Ld  + w7*D.x + w8*D.y;
    float u4 = w0*B.x + w1*B.y + w2*B.z + w3*C.x + w4*C.y + w5*C.z + w6*D.x + w7*D.y + w8*D.z;
    float u5 = w0*B.y + w1*B.z + w2*Tb  + w3*C.y + w4*C.z + w5*Tc  + w6*D.y + w7*D.z + w8*Td;

    p0 = fmaf(sc, u0, p0); p1 = fmaf(sc, u1, p1); p2 = fmaf(sc, u2, p2);
    p3 = fmaf(sc, u3, p3); p4 = fmaf(sc, u4, p4); p5 = fmaf(sc, u5, p5);

    float h0 = u0 + bias, h1 = u1 + bias, h2 = u2 + bias;
    float h3 = u3 + bias, h4 = u4 + bias, h5 = u5 + bias;
    s1 += ((h0 + h1) + (h2 + h3)) + (h4 + h5);
    float q0 = fmaf(h0, h0, h1 * h1);
    float q1 = fmaf(h2, h2, h3 * h3);
    float q2 = fmaf(h4, h4, h5 * h5);
    s2 += (q0 + q1) + q2;
  }

  {
    float* Pp = P + ((size_t)(b * GG + gr)) * NPIX;
    float3 v0; v0.x = p0; v0.y = p1; v0.z = p2;
    float3 v1; v1.x = p3; v1.y = p4; v1.z = p5;
    *(float3*)&Pp[offb] = v0;
    *(float3*)&Pp[offc] = v1;
  }

  // block-reduce s1,s2 (4 waves)
  #pragma unroll
  for (int off = 32; off; off >>= 1) {
    s1 += __shfl_down(s1, off);
    s2 += __shfl_down(s2, off);
  }
  __shared__ float r1[4], r2[4];
  if ((tid & 63) == 0) { r1[tid >> 6] = s1; r2[tid >> 6] = s2; }
  __syncthreads();
  if (tid == 0) {
    float a = r1[0] + r1[1] + r1[2] + r1[3];
    float q = r2[0] + r2[1] + r2[2] + r2[3];
    partials[bid * 2]     = a;
    partials[bid * 2 + 1] = q;
  }
}

// ---------------------------------------------------------------------------
// Kernel 2: fused coef + output. Each block (18 per batch) recomputes its
// batch's 32 rinv values + scalar D from partials, then
// out[b,p] = sigmoid( sum_g rinv[g]*P[b,g,p] + D ).  128 thr, 4 px/thread.
// ---------------------------------------------------------------------------
__global__ __launch_bounds__(128)
void k_out(const float* __restrict__ P, const float* __restrict__ partials,
           const float* __restrict__ dw_b, const float* __restrict__ gn_w,
           const float* __restrict__ gn_b, const float* __restrict__ proj_w,
           const float* __restrict__ proj_b, float* __restrict__ out) {
  const int b   = blockIdx.x / 18;
  const int blk = blockIdx.x % 18;
  __shared__ float rs[GG];
  __shared__ float Ds;

  if (threadIdx.x < GG) {
    const int gr = threadIdx.x;
    float s1 = 0.f, s2 = 0.f;
    #pragma unroll
    for (int t = 0; t < YT; ++t) {
      int o = (((b * GG + gr) * YT) + t) * 2;
      s1 += partials[o];
      s2 += partials[o + 1];
    }
    const float invN = 1.f / (float)(CPG * NPIX);
    float mean = s1 * invN;
    float var  = s2 * invN - mean * mean;
    float rinv = rsqrtf(var + 1e-5f);
    rs[gr] = rinv;
    float K = 0.f, E = 0.f;
    #pragma unroll
    for (int i = 0; i < CPG; ++i) {
      int c = gr * CPG + i;
      float pg = proj_w[c] * gn_w[c];
      K = fmaf(pg, dw_b[c] - mean, K);
      E = fmaf(proj_w[c], gn_b[c], E);
    }
    float contrib = fmaf(rinv, K, E);
    #pragma unroll
    for (int m = 16; m; m >>= 1) contrib += __shfl_xor(contrib, m, 32);
    if (gr == 0) Ds = contrib + proj_b[0];
  }
  __syncthreads();

  const int p = (blk * 128 + threadIdx.x) * 4;    // 18*128*4 = 9216
  const float* Pb = P + (size_t)b * GG * NPIX + p;
  float g0 = 0.f, g1 = 0.f, g2 = 0.f, g3 = 0.f;
  #pragma unroll
  for (int gr = 0; gr < GG; ++gr) {
    float4 v = *(const float4*)(Pb + (size_t)gr * NPIX);
    float rr = rs[gr];
    g0 = fmaf(rr, v.x, g0);
    g1 = fmaf(rr, v.y, g1);
    g2 = fmaf(rr, v.z, g2);
    g3 = fmaf(rr, v.w, g3);
  }
  const float d = Ds;
  float4 o;
  o.x = 1.f / (1.f + expf(-(g0 + d)));
  o.y = 1.f / (1.f + expf(-(g1 + d)));
  o.z = 1.f / (1.f + expf(-(g2 + d)));
  o.w = 1.f / (1.f + expf(-(g3 + d)));
  *(float4*)&out[(size_t)b * NPIX + p] = o;
}

// ---------------------------------------------------------------------------
extern "C" void kernel_launch(void* const* d_in, const int* in_sizes, int n_in,
                              void* d_out, int out_size, void* d_ws, size_t ws_size,
                              hipStream_t stream) {
  const float* x      = (const float*)d_in[0];
  const float* dw_w   = (const float*)d_in[1];
  const float* dw_b   = (const float*)d_in[2];
  const float* gn_w   = (const float*)d_in[3];
  const float* gn_b   = (const float*)d_in[4];
  const float* proj_w = (const float*)d_in[5];
  const float* proj_b = (const float*)d_in[6];
  float* out = (float*)d_out;

  const size_t P_BYTES = (size_t)16 * GG * NPIX * 4;     // fp32: 18,874,368 B
  float* P        = (float*)d_ws;
  float* partials = (float*)((char*)d_ws + P_BYTES);     // 3072*2 f32

  hipLaunchKernelGGL(k_main, dim3(16 * GG * YT), dim3(TPB), 0, stream,
                     x, dw_w, dw_b, gn_w, proj_w, P, partials);
  hipLaunchKernelGGL(k_out, dim3(16 * 18), dim3(128), 0, stream,
                     P, partials, dw_b, gn_w, gn_b, proj_w, proj_b, out);
}